// Round 6
// baseline (234.331 us; speedup 1.0000x reference)
//
#include <hip/hip_runtime.h>
#include <cmath>

// Problem constants
#define BATCH   64
#define NPG     1024           // nodes per graph
#define NODES   65536          // BATCH*NPG
#define EDGES   524288
#define FIN     14
#define NH      128
#define KP1     820
#define KP2     656

// ---------------------------------------------------------------------------
// CSR build (by dst): histogram -> 2-level exclusive scan -> fill
// ---------------------------------------------------------------------------
__global__ __launch_bounds__(256) void k_hist(
    const int* __restrict__ dst, int* __restrict__ cnt) {
  int e = blockIdx.x * 256 + threadIdx.x;
  atomicAdd(&cnt[dst[e]], 1);
}

__global__ __launch_bounds__(256) void k_scan_local(
    const int* __restrict__ cnt, int* __restrict__ rowptr,
    int* __restrict__ bsum) {
  __shared__ int s[256];
  int t = threadIdx.x, b = blockIdx.x;
  int v = cnt[b * 256 + t];
  s[t] = v;
  __syncthreads();
  for (int d = 1; d < 256; d <<= 1) {
    int add = (t >= d) ? s[t - d] : 0;
    __syncthreads();
    s[t] += add;
    __syncthreads();
  }
  rowptr[b * 256 + t] = s[t] - v;      // exclusive, block-local
  if (t == 255) bsum[b] = s[255];
}

// merged base-scan + final: each block redundantly scans bsum[256] in LDS
__global__ __launch_bounds__(256) void k_scan_final(
    int* __restrict__ rowptr, const int* __restrict__ bsum,
    int* __restrict__ cursor) {
  __shared__ int s[256];
  int t = threadIdx.x, b = blockIdx.x;
  int v = bsum[t];
  s[t] = v;
  __syncthreads();
  for (int d = 1; d < 256; d <<= 1) {
    int add = (t >= d) ? s[t - d] : 0;
    __syncthreads();
    s[t] += add;
    __syncthreads();
  }
  int base = (b == 0) ? 0 : s[b - 1];    // exclusive prefix of block b
  int id = b * 256 + t;
  int v2 = rowptr[id] + base;
  rowptr[id] = v2;
  cursor[id] = v2;
  if (id == 0) rowptr[NODES] = EDGES;
}

__global__ __launch_bounds__(256) void k_fill(
    const int* __restrict__ src, const int* __restrict__ dst,
    int* __restrict__ cursor, int* __restrict__ col) {
  int e = blockIdx.x * 256 + threadIdx.x;
  int pos = atomicAdd(&cursor[dst[e]], 1);
  col[pos] = src[e];
}

// ---------------------------------------------------------------------------
// fused weight prep: Wt2 transpose-concat + both pool-weight norms
// ---------------------------------------------------------------------------
__global__ __launch_bounds__(256) void k_prep(
    const float* __restrict__ Wrel, const float* __restrict__ Wroot,
    const float* __restrict__ p1w, const float* __restrict__ p2w,
    float* __restrict__ Wt, float* __restrict__ rn1, float* __restrict__ rn2) {
  int id = blockIdx.x * 256 + threadIdx.x;
  int k = id >> 7, o = id & 127;
  Wt[id] = (k < NH) ? Wrel[o * NH + k] : Wroot[o * NH + (k - NH)];
  if (blockIdx.x == 0) {
    __shared__ float red[4];
    int t = threadIdx.x;
    const float* w = (t < 128) ? p1w : p2w;
    int f = t & 127;
    float q = w[f] * w[f];
#pragma unroll
    for (int d = 32; d; d >>= 1) q += __shfl_xor(q, d);
    if ((t & 63) == 0) red[t >> 6] = q;
    __syncthreads();
    if (t == 0)   *rn1 = rsqrtf(red[0] + red[1]);
    if (t == 128) *rn2 = rsqrtf(red[2] + red[3]);
  }
}

// ---------------------------------------------------------------------------
// conv1 aggregation via CSR gather (XCD-swizzled for per-graph L2 locality)
// ---------------------------------------------------------------------------
__global__ __launch_bounds__(256) void k_gather1(
    const float* __restrict__ x, const int* __restrict__ rowptr,
    const int* __restrict__ col, float* __restrict__ agg1) {
  int bid = blockIdx.x;                       // 4096 blocks, 512 per XCD chunk
  int swz = (bid & 7) * 512 + (bid >> 3);
  int t = threadIdx.x;
  int gi = t >> 4, l = t & 15;
  int n = swz * 16 + gi;
  int rs = rowptr[n], re = rowptr[n + 1];
  if (l < FIN) {
    float acc = 0.f;
    for (int j = rs; j < re; ++j) {
      int v = col[j];
      acc += x[(size_t)v * FIN + l];
    }
    agg1[(size_t)n * FIN + l] = acc;
  }
}

// ---------------------------------------------------------------------------
// conv1 GEMM + relu + fused pool1 score.
// Block 256 thr / 64 nodes; thread = 4 nodes x 8 outs (cols og*4+j, 64+og*4+j)
// ---------------------------------------------------------------------------
__global__ __launch_bounds__(256) void k_gemm1(
    const float* __restrict__ x, const float* __restrict__ agg1,
    const float* __restrict__ Wrel, const float* __restrict__ brel,
    const float* __restrict__ Wroot, const float* __restrict__ p1w,
    const float* __restrict__ rn1p, float* __restrict__ h1,
    float* __restrict__ s1) {
  __shared__ float As[64 * FIN];
  __shared__ float Xs[64 * FIN];
  __shared__ float Wl[2 * FIN][NH];
  int t = threadIdx.x;
  int nb = blockIdx.x * 64;
  for (int i = t; i < 64 * FIN; i += 256) {
    As[i] = agg1[(size_t)nb * FIN + i];
    Xs[i] = x[(size_t)nb * FIN + i];
  }
  for (int i = t; i < NH * FIN; i += 256) {
    int o = i / FIN, k = i - o * FIN;
    Wl[k][o]       = Wrel[i];
    Wl[k + FIN][o] = Wroot[i];
  }
  __syncthreads();
  int og = t & 15, ng = t >> 4, ra = ng * 4;
  float bb[8], pw[8];
#pragma unroll
  for (int j = 0; j < 4; ++j) {
    int c0 = og * 4 + j, c1 = 64 + og * 4 + j;
    bb[j] = brel[c0]; bb[j + 4] = brel[c1];
    pw[j] = p1w[c0];  pw[j + 4] = p1w[c1];
  }
  float acc[4][8];
#pragma unroll
  for (int i = 0; i < 4; ++i)
#pragma unroll
    for (int j = 0; j < 8; ++j) acc[i][j] = bb[j];
#pragma unroll
  for (int k = 0; k < FIN; ++k) {
    float4 w0 = *(const float4*)&Wl[k][og * 4];
    float4 w1 = *(const float4*)&Wl[k][64 + og * 4];
#pragma unroll
    for (int i = 0; i < 4; ++i) {
      float a = As[(ra + i) * FIN + k];
      acc[i][0] += a * w0.x; acc[i][1] += a * w0.y;
      acc[i][2] += a * w0.z; acc[i][3] += a * w0.w;
      acc[i][4] += a * w1.x; acc[i][5] += a * w1.y;
      acc[i][6] += a * w1.z; acc[i][7] += a * w1.w;
    }
  }
#pragma unroll
  for (int k = 0; k < FIN; ++k) {
    float4 w0 = *(const float4*)&Wl[FIN + k][og * 4];
    float4 w1 = *(const float4*)&Wl[FIN + k][64 + og * 4];
#pragma unroll
    for (int i = 0; i < 4; ++i) {
      float a = Xs[(ra + i) * FIN + k];
      acc[i][0] += a * w0.x; acc[i][1] += a * w0.y;
      acc[i][2] += a * w0.z; acc[i][3] += a * w0.w;
      acc[i][4] += a * w1.x; acc[i][5] += a * w1.y;
      acc[i][6] += a * w1.z; acc[i][7] += a * w1.w;
    }
  }
  float rnorm = *rn1p;
#pragma unroll
  for (int i = 0; i < 4; ++i) {
    int n = nb + ra + i;
    float pv = 0.f;
#pragma unroll
    for (int j = 0; j < 8; ++j) {
      float v = fmaxf(acc[i][j], 0.f);
      acc[i][j] = v;
      pv += v * pw[j];
    }
    *(float4*)(h1 + (size_t)n * NH + og * 4) =
        make_float4(acc[i][0], acc[i][1], acc[i][2], acc[i][3]);
    *(float4*)(h1 + (size_t)n * NH + 64 + og * 4) =
        make_float4(acc[i][4], acc[i][5], acc[i][6], acc[i][7]);
    pv += __shfl_xor(pv, 1);
    pv += __shfl_xor(pv, 2);
    pv += __shfl_xor(pv, 4);
    pv += __shfl_xor(pv, 8);
    if (og == 0) s1[n] = tanhf(pv * rnorm);
  }
}

// ---------------------------------------------------------------------------
// exact per-graph top-K: 512 threads, all-active bitonic over 1024 keys
// ---------------------------------------------------------------------------
__global__ __launch_bounds__(512) void k_topk(
    const float* __restrict__ score, const int* __restrict__ mask_in,
    int* __restrict__ kept, int K) {
  __shared__ unsigned long long keys[1024];
  int t = threadIdx.x, g = blockIdx.x;
  for (int i = t; i < 1024; i += 512) {
    int n = g * NPG + i;
    unsigned int inv;
    if (mask_in && !mask_in[n]) {
      inv = 0xFFFFFFFFu;
    } else {
      unsigned int u   = __float_as_uint(score[n]);
      unsigned int ord = (u & 0x80000000u) ? ~u : (u | 0x80000000u);
      inv = ~ord;
    }
    keys[i] = ((unsigned long long)inv << 32) | (unsigned int)i;
  }
  __syncthreads();
  for (int k = 2; k <= 1024; k <<= 1) {
    for (int j = k >> 1; j > 0; j >>= 1) {
      int i = ((t & ~(j - 1)) << 1) | (t & (j - 1));
      int p = i | j;
      unsigned long long a = keys[i], b = keys[p];
      bool up = ((i & k) == 0);
      if ((a > b) == up) { keys[i] = b; keys[p] = a; }
      __syncthreads();
    }
  }
  for (int i = t; i < 1024; i += 512) {
    int idx = (int)(keys[i] & 0xFFFFFFFFu);
    kept[g * NPG + idx] = (i < K) ? 1 : 0;
  }
}

// ---------------------------------------------------------------------------
// readout partials over kept nodes: v = h[n]*s[n]  (read-only)
// 1024 blocks x 256 thr; block = 64-node chunk, two rows in flight
// partial slot = blockIdx*2 + half  (2048 slots total)
// ---------------------------------------------------------------------------
__global__ __launch_bounds__(256) void k_readout(
    const float* __restrict__ h, const float* __restrict__ s,
    const int* __restrict__ kept, float* __restrict__ psum,
    float* __restrict__ pmax) {
  int g = blockIdx.x >> 4, c = blockIdx.x & 15;
  int f = threadIdx.x & 127, half = threadIdx.x >> 7;
  int nbase = g * NPG + c * 64 + half;
  float sum = 0.f, mx = -1e30f;
  for (int i = 0; i < 64; i += 2) {
    int n = nbase + i;
    if (kept[n]) {
      float v = h[(size_t)n * NH + f] * s[n];
      sum += v;
      mx = fmaxf(mx, v);
    }
  }
  int slot = blockIdx.x * 2 + half;
  psum[(size_t)slot * NH + f] = sum;
  pmax[(size_t)slot * NH + f] = mx;
}

// ---------------------------------------------------------------------------
// conv2 aggregation: one wave per kept dst row; scale s1*kept applied on the
// fly (sx never materialized). XCD-swizzled: graph-local L2 reuse of h1 rows.
// ---------------------------------------------------------------------------
__global__ __launch_bounds__(256) void k_gather2(
    const float* __restrict__ h1, const float* __restrict__ s1,
    const int* __restrict__ rowptr, const int* __restrict__ col,
    const int* __restrict__ kept1, float* __restrict__ agg2) {
  int bid = blockIdx.x;                       // 16384 blocks, 2048 per XCD
  int swz = (bid & 7) * 2048 + (bid >> 3);
  int wave = threadIdx.x >> 6, lane = threadIdx.x & 63;
  int d = swz * 4 + wave;
  if (!kept1[d]) return;                      // row never consumed downstream
  int rs = rowptr[d], re = rowptr[d + 1];
  int deg = re - rs;
  int colv = 0; float sv = 0.f;
  if (lane < deg) {
    colv = col[rs + lane];
    sv = kept1[colv] ? s1[colv] : 0.f;
  }
  int m = deg < 64 ? deg : 64;
  float ax = 0.f, ay = 0.f;
  int nfull = m & ~3;
  int j = 0;
  for (; j < nfull; j += 4) {
    int v0 = __shfl(colv, j);
    int v1 = __shfl(colv, j + 1);
    int v2 = __shfl(colv, j + 2);
    int v3 = __shfl(colv, j + 3);
    float f0 = __shfl(sv, j);
    float f1 = __shfl(sv, j + 1);
    float f2 = __shfl(sv, j + 2);
    float f3 = __shfl(sv, j + 3);
    float2 a = *(const float2*)(h1 + (size_t)v0 * NH + lane * 2);
    float2 b = *(const float2*)(h1 + (size_t)v1 * NH + lane * 2);
    float2 c = *(const float2*)(h1 + (size_t)v2 * NH + lane * 2);
    float2 e = *(const float2*)(h1 + (size_t)v3 * NH + lane * 2);
    ax += a.x * f0 + b.x * f1 + c.x * f2 + e.x * f3;
    ay += a.y * f0 + b.y * f1 + c.y * f2 + e.y * f3;
  }
  for (; j < m; ++j) {
    int v = __shfl(colv, j);
    float f = __shfl(sv, j);
    float2 a = *(const float2*)(h1 + (size_t)v * NH + lane * 2);
    ax += a.x * f; ay += a.y * f;
  }
  for (int jj = rs + 64; jj < re; ++jj) {      // deg>64 fallback (≈never)
    int v = col[jj];
    float f = kept1[v] ? s1[v] : 0.f;
    float2 a = *(const float2*)(h1 + (size_t)v * NH + lane * 2);
    ax += a.x * f; ay += a.y * f;
  }
  *(float2*)(agg2 + (size_t)d * NH + lane * 2) = make_float2(ax, ay);
}

// ---------------------------------------------------------------------------
// conv2 GEMM (K=256 = [agg2 | h1*s1]) + bias + relu + fused pool2 score.
// Block = 256 thr, 64 nodes x 128 outs; thread = 4 nodes x 8 outs.
// kk unrolled by 4 with float4 A-reads: 12 b128 LDS reads / 128 FMA.
// No staging masks: dropped agg2 rows may hold garbage (finite), their h2 is
// never written and their s2 is excluded by topk2's mask_in. 1024 blocks =
// 4 blocks/CU (r4 occupancy). h2 ALIASES agg2 (own rows only). XCD-swizzled
// to match k_gather2's writer map.
// ---------------------------------------------------------------------------
__global__ __launch_bounds__(256) void k_gemm2(
    const float* __restrict__ agg2, const float* __restrict__ h1,
    const float* __restrict__ s1, const int* __restrict__ kept1,
    const float* __restrict__ Wt, const float* __restrict__ b2,
    const float* __restrict__ p2w, const float* __restrict__ rnorm2p,
    float* __restrict__ h2, float* __restrict__ s2) {
  __shared__ float Al[64][36];          // 9.2 KB; rows 8 apart alias = 2-way ok
  __shared__ float Wl[32 * NH];         // 16 KB
  __shared__ float rs_l[64];            // s1 per kept row (0 if dropped)
  __shared__ float ms_l[64];            // kept mask (epilogue write gate)
  int t = threadIdx.x;
  int bid = blockIdx.x;                 // 1024 blocks, 128 per XCD chunk
  int swz = (bid & 7) * 128 + (bid >> 3);
  int nb = swz * 64;
  if (t < 64) {
    int k = kept1[nb + t];
    ms_l[t] = k ? 1.f : 0.f;
    rs_l[t] = k ? s1[nb + t] : 0.f;
  }
  int og = t & 15, ng = t >> 4, ra = ng * 4;
  float acc[4][8];
#pragma unroll
  for (int i = 0; i < 4; ++i)
#pragma unroll
    for (int j = 0; j < 8; ++j) acc[i][j] = 0.f;

  int sr = t >> 2;                      // staging row 0..63
  int sc = (t & 3) * 8;                 // staging col start
#pragma unroll 1
  for (int kc = 0; kc < 8; ++kc) {
    __syncthreads();
    const float* S = (kc < 4) ? agg2 : h1;
    int kb = (kc & 3) * 32;
    float4 v0 = *(const float4*)(S + (size_t)(nb + sr) * NH + kb + sc);
    float4 v1 = *(const float4*)(S + (size_t)(nb + sr) * NH + kb + sc + 4);
    if (kc >= 4) {
      float sc0 = rs_l[sr];
      v0.x *= sc0; v0.y *= sc0; v0.z *= sc0; v0.w *= sc0;
      v1.x *= sc0; v1.y *= sc0; v1.z *= sc0; v1.w *= sc0;
    }
    *(float4*)&Al[sr][sc]     = v0;
    *(float4*)&Al[sr][sc + 4] = v1;
    {
      const float4* wsrc = (const float4*)(Wt + (size_t)kc * 32 * NH);
      float4* wdst = (float4*)Wl;
      wdst[t]       = wsrc[t];
      wdst[t + 256] = wsrc[t + 256];
      wdst[t + 512] = wsrc[t + 512];
      wdst[t + 768] = wsrc[t + 768];
    }
    __syncthreads();
#pragma unroll
    for (int kq = 0; kq < 8; ++kq) {
      float4 a0 = *(const float4*)&Al[ra + 0][kq * 4];
      float4 a1 = *(const float4*)&Al[ra + 1][kq * 4];
      float4 a2 = *(const float4*)&Al[ra + 2][kq * 4];
      float4 a3 = *(const float4*)&Al[ra + 3][kq * 4];
#pragma unroll
      for (int u = 0; u < 4; ++u) {
        int kk = kq * 4 + u;
        float4 w0 = *(const float4*)&Wl[kk * NH + og * 4];
        float4 w1 = *(const float4*)&Wl[kk * NH + 64 + og * 4];
        float e0 = (u == 0) ? a0.x : (u == 1) ? a0.y : (u == 2) ? a0.z : a0.w;
        float e1 = (u == 0) ? a1.x : (u == 1) ? a1.y : (u == 2) ? a1.z : a1.w;
        float e2 = (u == 0) ? a2.x : (u == 1) ? a2.y : (u == 2) ? a2.z : a2.w;
        float e3 = (u == 0) ? a3.x : (u == 1) ? a3.y : (u == 2) ? a3.z : a3.w;
        acc[0][0] += e0 * w0.x; acc[0][1] += e0 * w0.y;
        acc[0][2] += e0 * w0.z; acc[0][3] += e0 * w0.w;
        acc[0][4] += e0 * w1.x; acc[0][5] += e0 * w1.y;
        acc[0][6] += e0 * w1.z; acc[0][7] += e0 * w1.w;
        acc[1][0] += e1 * w0.x; acc[1][1] += e1 * w0.y;
        acc[1][2] += e1 * w0.z; acc[1][3] += e1 * w0.w;
        acc[1][4] += e1 * w1.x; acc[1][5] += e1 * w1.y;
        acc[1][6] += e1 * w1.z; acc[1][7] += e1 * w1.w;
        acc[2][0] += e2 * w0.x; acc[2][1] += e2 * w0.y;
        acc[2][2] += e2 * w0.z; acc[2][3] += e2 * w0.w;
        acc[2][4] += e2 * w1.x; acc[2][5] += e2 * w1.y;
        acc[2][6] += e2 * w1.z; acc[2][7] += e2 * w1.w;
        acc[3][0] += e3 * w0.x; acc[3][1] += e3 * w0.y;
        acc[3][2] += e3 * w0.z; acc[3][3] += e3 * w0.w;
        acc[3][4] += e3 * w1.x; acc[3][5] += e3 * w1.y;
        acc[3][6] += e3 * w1.z; acc[3][7] += e3 * w1.w;
      }
    }
  }

  float rnorm = *rnorm2p;
  float bb[8], pw[8];
#pragma unroll
  for (int j = 0; j < 4; ++j) {
    int c0 = og * 4 + j, c1 = 64 + og * 4 + j;
    bb[j] = b2[c0]; bb[j + 4] = b2[c1];
    pw[j] = p2w[c0]; pw[j + 4] = p2w[c1];
  }
#pragma unroll
  for (int i = 0; i < 4; ++i) {
    int row = ra + i;
    int n = nb + row;
    float pv = 0.f;
#pragma unroll
    for (int j = 0; j < 8; ++j) {
      float v = fmaxf(acc[i][j] + bb[j], 0.f);
      acc[i][j] = v;
      pv += v * pw[j];
    }
    if (ms_l[row] != 0.f) {              // kept2 subset of kept1 -> safe skip
      *(float4*)(h2 + (size_t)n * NH + og * 4) =
          make_float4(acc[i][0], acc[i][1], acc[i][2], acc[i][3]);
      *(float4*)(h2 + (size_t)n * NH + 64 + og * 4) =
          make_float4(acc[i][4], acc[i][5], acc[i][6], acc[i][7]);
    }
    pv += __shfl_xor(pv, 1);
    pv += __shfl_xor(pv, 2);
    pv += __shfl_xor(pv, 4);
    pv += __shfl_xor(pv, 8);
    if (og == 0) s2[n] = tanhf(pv * rnorm);
  }
}

// ---------------------------------------------------------------------------
// final combine (32 partial slots per graph)
// ---------------------------------------------------------------------------
__global__ __launch_bounds__(256) void k_final(
    const float* __restrict__ psum1, const float* __restrict__ pmax1,
    const float* __restrict__ psum2, const float* __restrict__ pmax2,
    float* __restrict__ out) {
  int g = blockIdx.x, t = threadIdx.x;
  if (t < 128) {
    float a = 0.f, b = 0.f;
#pragma unroll
    for (int c = 0; c < 32; ++c) {
      a += psum1[(size_t)(g * 32 + c) * NH + t];
      b += psum2[(size_t)(g * 32 + c) * NH + t];
    }
    out[(size_t)g * 256 + t] = a / (float)KP1 + b / (float)KP2;
  } else {
    int f = t - 128;
    float a = -1e30f, b = -1e30f;
#pragma unroll
    for (int c = 0; c < 32; ++c) {
      a = fmaxf(a, pmax1[(size_t)(g * 32 + c) * NH + f]);
      b = fmaxf(b, pmax2[(size_t)(g * 32 + c) * NH + f]);
    }
    out[(size_t)g * 256 + t] = a + b;
  }
}

// ---------------------------------------------------------------------------
extern "C" void kernel_launch(void* const* d_in, const int* in_sizes, int n_in,
                              void* d_out, int out_size, void* d_ws, size_t ws_size,
                              hipStream_t stream) {
  const float* x     = (const float*)d_in[0];
  const int*   eidx  = (const int*)d_in[1];
  const int*   src   = eidx;
  const int*   dst   = eidx + EDGES;
  const float* W1rel = (const float*)d_in[3];
  const float* b1    = (const float*)d_in[4];
  const float* W1rt  = (const float*)d_in[5];
  const float* p1w   = (const float*)d_in[6];
  const float* W2rel = (const float*)d_in[7];
  const float* b2    = (const float*)d_in[8];
  const float* W2rt  = (const float*)d_in[9];
  const float* p2w   = (const float*)d_in[10];
  float* out = (float*)d_out;

  // workspace layout (floats) — h2 aliases agg2 (see k_gemm2)
  float* ws = (float*)d_ws;
  size_t off = 0;
  float* h1    = ws + off; off += (size_t)NODES * NH;
  float* agg2  = ws + off; off += (size_t)NODES * NH;
  float* h2    = agg2;
  float* agg1  = ws + off; off += (size_t)NODES * FIN;
  float* s1    = ws + off; off += NODES;
  float* s2    = ws + off; off += NODES;
  int*   kept1 = (int*)(ws + off); off += NODES;
  int*   kept2 = (int*)(ws + off); off += NODES;
  float* psum1 = ws + off; off += 2048 * NH;
  float* pmax1 = ws + off; off += 2048 * NH;
  float* psum2 = ws + off; off += 2048 * NH;
  float* pmax2 = ws + off; off += 2048 * NH;
  float* Wt2   = ws + off; off += 256 * NH;
  float* rn1   = ws + off; off += 1;
  float* rn2   = ws + off; off += 1;
  int*   cnt     = (int*)(ws + off); off += NODES;
  int*   rowptr  = (int*)(ws + off); off += NODES + 1;
  int*   cursor  = (int*)(ws + off); off += NODES;
  int*   bsum    = (int*)(ws + off); off += 256;
  int*   col     = (int*)(ws + off); off += EDGES;

  // ---- CSR build ----
  hipMemsetAsync(cnt, 0, (size_t)NODES * sizeof(int), stream);
  k_hist<<<EDGES / 256, 256, 0, stream>>>(dst, cnt);
  k_scan_local<<<NODES / 256, 256, 0, stream>>>(cnt, rowptr, bsum);
  k_scan_final<<<NODES / 256, 256, 0, stream>>>(rowptr, bsum, cursor);
  k_fill<<<EDGES / 256, 256, 0, stream>>>(src, dst, cursor, col);

  // ---- weight prep (independent) ----
  k_prep<<<128, 256, 0, stream>>>(W2rel, W2rt, p1w, p2w, Wt2, rn1, rn2);

  // ---- layer 1 ----
  k_gather1<<<NODES / 16, 256, 0, stream>>>(x, rowptr, col, agg1);
  k_gemm1<<<NODES / 64, 256, 0, stream>>>(x, agg1, W1rel, b1, W1rt, p1w, rn1,
                                          h1, s1);
  k_topk<<<BATCH, 512, 0, stream>>>(s1, nullptr, kept1, KP1);
  k_readout<<<BATCH * 16, 256, 0, stream>>>(h1, s1, kept1, psum1, pmax1);

  // ---- layer 2 ----
  k_gather2<<<NODES / 4, 256, 0, stream>>>(h1, s1, rowptr, col, kept1, agg2);
  k_gemm2<<<NODES / 64, 256, 0, stream>>>(agg2, h1, s1, kept1, Wt2, b2, p2w,
                                          rn2, h2, s2);
  k_topk<<<BATCH, 512, 0, stream>>>(s2, kept1, kept2, KP2);
  k_readout<<<BATCH * 16, 256, 0, stream>>>(h2, s2, kept2, psum2, pmax2);
  k_final<<<BATCH, 256, 0, stream>>>(psum1, pmax1, psum2, pmax2, out);
}

// Round 7
// 210.245 us; speedup vs baseline: 1.1146x; 1.1146x over previous
//
#include <hip/hip_runtime.h>
#include <hip/hip_bf16.h>
#include <cmath>

// Problem constants
#define BATCH   64
#define NPG     1024           // nodes per graph
#define NODES   65536          // BATCH*NPG
#define EDGES   524288
#define FIN     14
#define NH      128
#define KP1     820
#define KP2     656

typedef __attribute__((ext_vector_type(8))) short bf16x8;
typedef __attribute__((ext_vector_type(4))) float f32x4;

static __device__ __forceinline__ unsigned short f2bf(float f) {
  __hip_bfloat16 h = __float2bfloat16(f);
  return *reinterpret_cast<unsigned short*>(&h);
}

// ---------------------------------------------------------------------------
// CSR build (by dst): histogram -> 2-level exclusive scan -> fill
// ---------------------------------------------------------------------------
__global__ __launch_bounds__(256) void k_hist(
    const int* __restrict__ dst, int* __restrict__ cnt) {
  int e = blockIdx.x * 256 + threadIdx.x;
  atomicAdd(&cnt[dst[e]], 1);
}

__global__ __launch_bounds__(256) void k_scan_local(
    const int* __restrict__ cnt, int* __restrict__ rowptr,
    int* __restrict__ bsum) {
  __shared__ int s[256];
  int t = threadIdx.x, b = blockIdx.x;
  int v = cnt[b * 256 + t];
  s[t] = v;
  __syncthreads();
  for (int d = 1; d < 256; d <<= 1) {
    int add = (t >= d) ? s[t - d] : 0;
    __syncthreads();
    s[t] += add;
    __syncthreads();
  }
  rowptr[b * 256 + t] = s[t] - v;      // exclusive, block-local
  if (t == 255) bsum[b] = s[255];
}

// merged base-scan + final: each block redundantly scans bsum[256] in LDS
__global__ __launch_bounds__(256) void k_scan_final(
    int* __restrict__ rowptr, const int* __restrict__ bsum,
    int* __restrict__ cursor) {
  __shared__ int s[256];
  int t = threadIdx.x, b = blockIdx.x;
  int v = bsum[t];
  s[t] = v;
  __syncthreads();
  for (int d = 1; d < 256; d <<= 1) {
    int add = (t >= d) ? s[t - d] : 0;
    __syncthreads();
    s[t] += add;
    __syncthreads();
  }
  int base = (b == 0) ? 0 : s[b - 1];    // exclusive prefix of block b
  int id = b * 256 + t;
  int v2 = rowptr[id] + base;
  rowptr[id] = v2;
  cursor[id] = v2;
  if (id == 0) rowptr[NODES] = EDGES;
}

__global__ __launch_bounds__(256) void k_fill(
    const int* __restrict__ src, const int* __restrict__ dst,
    int* __restrict__ cursor, int* __restrict__ col) {
  int e = blockIdx.x * 256 + threadIdx.x;
  int pos = atomicAdd(&cursor[dst[e]], 1);
  col[pos] = src[e];
}

// ---------------------------------------------------------------------------
// conv1 aggregation via CSR gather (XCD-swizzled for per-graph L2 locality)
// ---------------------------------------------------------------------------
__global__ __launch_bounds__(256) void k_gather1(
    const float* __restrict__ x, const int* __restrict__ rowptr,
    const int* __restrict__ col, float* __restrict__ agg1) {
  int bid = blockIdx.x;                       // 4096 blocks, 512 per XCD chunk
  int swz = (bid & 7) * 512 + (bid >> 3);
  int t = threadIdx.x;
  int gi = t >> 4, l = t & 15;
  int n = swz * 16 + gi;
  int rs = rowptr[n], re = rowptr[n + 1];
  if (l < FIN) {
    float acc = 0.f;
    for (int j = rs; j < re; ++j) {
      int v = col[j];
      acc += x[(size_t)v * FIN + l];
    }
    agg1[(size_t)n * FIN + l] = acc;
  }
}

// ---------------------------------------------------------------------------
// conv1 GEMM + relu + fused pool1 score (norm computed inline via shfl).
// Block 256 thr / 64 nodes; thread = 4 nodes x 8 outs (cols og*4+j, 64+og*4+j)
// ---------------------------------------------------------------------------
__global__ __launch_bounds__(256) void k_gemm1(
    const float* __restrict__ x, const float* __restrict__ agg1,
    const float* __restrict__ Wrel, const float* __restrict__ brel,
    const float* __restrict__ Wroot, const float* __restrict__ p1w,
    float* __restrict__ h1, float* __restrict__ s1) {
  __shared__ float As[64 * FIN];
  __shared__ float Xs[64 * FIN];
  __shared__ float Wl[2 * FIN][NH];
  int t = threadIdx.x;
  int nb = blockIdx.x * 64;
  for (int i = t; i < 64 * FIN; i += 256) {
    As[i] = agg1[(size_t)nb * FIN + i];
    Xs[i] = x[(size_t)nb * FIN + i];
  }
  for (int i = t; i < NH * FIN; i += 256) {
    int o = i / FIN, k = i - o * FIN;
    Wl[k][o]       = Wrel[i];
    Wl[k + FIN][o] = Wroot[i];
  }
  __syncthreads();
  int og = t & 15, ng = t >> 4, ra = ng * 4;
  float bb[8], pw[8];
#pragma unroll
  for (int j = 0; j < 4; ++j) {
    int c0 = og * 4 + j, c1 = 64 + og * 4 + j;
    bb[j] = brel[c0]; bb[j + 4] = brel[c1];
    pw[j] = p1w[c0];  pw[j + 4] = p1w[c1];
  }
  // rn1 = 1/||p1w||: 16-lane og-group covers all 128 cols
  float q = 0.f;
#pragma unroll
  for (int j = 0; j < 8; ++j) q += pw[j] * pw[j];
  q += __shfl_xor(q, 1); q += __shfl_xor(q, 2);
  q += __shfl_xor(q, 4); q += __shfl_xor(q, 8);
  float rnorm = rsqrtf(q);

  float acc[4][8];
#pragma unroll
  for (int i = 0; i < 4; ++i)
#pragma unroll
    for (int j = 0; j < 8; ++j) acc[i][j] = bb[j];
#pragma unroll
  for (int k = 0; k < FIN; ++k) {
    float4 w0 = *(const float4*)&Wl[k][og * 4];
    float4 w1 = *(const float4*)&Wl[k][64 + og * 4];
#pragma unroll
    for (int i = 0; i < 4; ++i) {
      float a = As[(ra + i) * FIN + k];
      acc[i][0] += a * w0.x; acc[i][1] += a * w0.y;
      acc[i][2] += a * w0.z; acc[i][3] += a * w0.w;
      acc[i][4] += a * w1.x; acc[i][5] += a * w1.y;
      acc[i][6] += a * w1.z; acc[i][7] += a * w1.w;
    }
  }
#pragma unroll
  for (int k = 0; k < FIN; ++k) {
    float4 w0 = *(const float4*)&Wl[FIN + k][og * 4];
    float4 w1 = *(const float4*)&Wl[FIN + k][64 + og * 4];
#pragma unroll
    for (int i = 0; i < 4; ++i) {
      float a = Xs[(ra + i) * FIN + k];
      acc[i][0] += a * w0.x; acc[i][1] += a * w0.y;
      acc[i][2] += a * w0.z; acc[i][3] += a * w0.w;
      acc[i][4] += a * w1.x; acc[i][5] += a * w1.y;
      acc[i][6] += a * w1.z; acc[i][7] += a * w1.w;
    }
  }
#pragma unroll
  for (int i = 0; i < 4; ++i) {
    int n = nb + ra + i;
    float pv = 0.f;
#pragma unroll
    for (int j = 0; j < 8; ++j) {
      float v = fmaxf(acc[i][j], 0.f);
      acc[i][j] = v;
      pv += v * pw[j];
    }
    *(float4*)(h1 + (size_t)n * NH + og * 4) =
        make_float4(acc[i][0], acc[i][1], acc[i][2], acc[i][3]);
    *(float4*)(h1 + (size_t)n * NH + 64 + og * 4) =
        make_float4(acc[i][4], acc[i][5], acc[i][6], acc[i][7]);
    pv += __shfl_xor(pv, 1);
    pv += __shfl_xor(pv, 2);
    pv += __shfl_xor(pv, 4);
    pv += __shfl_xor(pv, 8);
    if (og == 0) s1[n] = tanhf(pv * rnorm);
  }
}

// ---------------------------------------------------------------------------
// exact per-graph top-K: 512 threads, all-active bitonic over 1024 keys
// ---------------------------------------------------------------------------
__global__ __launch_bounds__(512) void k_topk(
    const float* __restrict__ score, const int* __restrict__ mask_in,
    int* __restrict__ kept, int K) {
  __shared__ unsigned long long keys[1024];
  int t = threadIdx.x, g = blockIdx.x;
  for (int i = t; i < 1024; i += 512) {
    int n = g * NPG + i;
    unsigned int inv;
    if (mask_in && !mask_in[n]) {
      inv = 0xFFFFFFFFu;
    } else {
      unsigned int u   = __float_as_uint(score[n]);
      unsigned int ord = (u & 0x80000000u) ? ~u : (u | 0x80000000u);
      inv = ~ord;
    }
    keys[i] = ((unsigned long long)inv << 32) | (unsigned int)i;
  }
  __syncthreads();
  for (int k = 2; k <= 1024; k <<= 1) {
    for (int j = k >> 1; j > 0; j >>= 1) {
      int i = ((t & ~(j - 1)) << 1) | (t & (j - 1));
      int p = i | j;
      unsigned long long a = keys[i], b = keys[p];
      bool up = ((i & k) == 0);
      if ((a > b) == up) { keys[i] = b; keys[p] = a; }
      __syncthreads();
    }
  }
  for (int i = t; i < 1024; i += 512) {
    int idx = (int)(keys[i] & 0xFFFFFFFFu);
    kept[g * NPG + idx] = (i < K) ? 1 : 0;
  }
}

// ---------------------------------------------------------------------------
// readout partials over kept nodes: v = h[n]*s[n]  (read-only)
// ---------------------------------------------------------------------------
__global__ __launch_bounds__(256) void k_readout(
    const float* __restrict__ h, const float* __restrict__ s,
    const int* __restrict__ kept, float* __restrict__ psum,
    float* __restrict__ pmax) {
  int g = blockIdx.x >> 4, c = blockIdx.x & 15;
  int f = threadIdx.x & 127, half = threadIdx.x >> 7;
  int nbase = g * NPG + c * 64 + half;
  float sum = 0.f, mx = -1e30f;
  for (int i = 0; i < 64; i += 2) {
    int n = nbase + i;
    if (kept[n]) {
      float v = h[(size_t)n * NH + f] * s[n];
      sum += v;
      mx = fmaxf(mx, v);
    }
  }
  int slot = blockIdx.x * 2 + half;
  psum[(size_t)slot * NH + f] = sum;
  pmax[(size_t)slot * NH + f] = mx;
}

// ---------------------------------------------------------------------------
// conv2 aggregation: one wave per kept dst row; scale s1*kept applied on the
// fly. XCD-swizzled: graph-local L2 reuse of h1 rows.
// ---------------------------------------------------------------------------
__global__ __launch_bounds__(256) void k_gather2(
    const float* __restrict__ h1, const float* __restrict__ s1,
    const int* __restrict__ rowptr, const int* __restrict__ col,
    const int* __restrict__ kept1, float* __restrict__ agg2) {
  int bid = blockIdx.x;                       // 16384 blocks, 2048 per XCD
  int swz = (bid & 7) * 2048 + (bid >> 3);
  int wave = threadIdx.x >> 6, lane = threadIdx.x & 63;
  int d = swz * 4 + wave;
  if (!kept1[d]) return;                      // row never consumed downstream
  int rs = rowptr[d], re = rowptr[d + 1];
  int deg = re - rs;
  int colv = 0; float sv = 0.f;
  if (lane < deg) {
    colv = col[rs + lane];
    sv = kept1[colv] ? s1[colv] : 0.f;
  }
  int m = deg < 64 ? deg : 64;
  float ax = 0.f, ay = 0.f;
  int nfull = m & ~3;
  int j = 0;
  for (; j < nfull; j += 4) {
    int v0 = __shfl(colv, j);
    int v1 = __shfl(colv, j + 1);
    int v2 = __shfl(colv, j + 2);
    int v3 = __shfl(colv, j + 3);
    float f0 = __shfl(sv, j);
    float f1 = __shfl(sv, j + 1);
    float f2 = __shfl(sv, j + 2);
    float f3 = __shfl(sv, j + 3);
    float2 a = *(const float2*)(h1 + (size_t)v0 * NH + lane * 2);
    float2 b = *(const float2*)(h1 + (size_t)v1 * NH + lane * 2);
    float2 c = *(const float2*)(h1 + (size_t)v2 * NH + lane * 2);
    float2 e = *(const float2*)(h1 + (size_t)v3 * NH + lane * 2);
    ax += a.x * f0 + b.x * f1 + c.x * f2 + e.x * f3;
    ay += a.y * f0 + b.y * f1 + c.y * f2 + e.y * f3;
  }
  for (; j < m; ++j) {
    int v = __shfl(colv, j);
    float f = __shfl(sv, j);
    float2 a = *(const float2*)(h1 + (size_t)v * NH + lane * 2);
    ax += a.x * f; ay += a.y * f;
  }
  for (int jj = rs + 64; jj < re; ++jj) {      // deg>64 fallback (≈never)
    int v = col[jj];
    float f = kept1[v] ? s1[v] : 0.f;
    float2 a = *(const float2*)(h1 + (size_t)v * NH + lane * 2);
    ax += a.x * f; ay += a.y * f;
  }
  *(float2*)(agg2 + (size_t)d * NH + lane * 2) = make_float2(ax, ay);
}

// ---------------------------------------------------------------------------
// conv2 via bf16 MFMA: h2 = relu([agg2 | h1*s1*kept] @ [W2rel|W2root]^T + b2)
// + fused pool2 score. Block = 256 thr / 4 waves, tile 64 nodes x 128 outs.
// Chunks: ch0 = agg2 x W2rel, ch1 = (h1*s1) x W2root (K=128 each, f32 acc).
// LDS bf16 tiles XOR-swizzled (k ^= (row&7)<<3): 256B rows would otherwise be
// a 16-way bank conflict on fragment reads (G4). Fragment layout per m97/m89:
// A,B: row=lane&15, k=(lane>>4)*8..+7 (K-contig bf16x8); D: col=lane&15,
// row=(lane>>4)*4+reg. W2rel/W2root are [o][k] = B^T form -> used directly.
// h2 ALIASES agg2 (own rows only); dropped rows: h2 not written, s2 garbage
// but masked by topk2's mask_in. XCD-swizzle matches gather2's writer map.
// ---------------------------------------------------------------------------
__global__ __launch_bounds__(256) void k_gemm2(
    const float* __restrict__ agg2, const float* __restrict__ h1,
    const float* __restrict__ s1, const int* __restrict__ kept1,
    const float* __restrict__ W2rel, const float* __restrict__ W2rt,
    const float* __restrict__ b2, const float* __restrict__ p2w,
    float* __restrict__ h2, float* __restrict__ s2) {
  __shared__ unsigned short Asm[64][128];    // bf16, swizzled (16 KB)
  __shared__ unsigned short Wsm[128][128];   // bf16, swizzled (32 KB)
  __shared__ float rs_l[64];
  __shared__ int   ms_l[64];
  int t = threadIdx.x;
  int bid = blockIdx.x;                 // 1024 blocks, 128 per XCD chunk
  int swz = (bid & 7) * 128 + (bid >> 3);
  int nb = swz * 64;
  if (t < 64) {
    int k = kept1[nb + t];
    ms_l[t] = k;
    rs_l[t] = k ? s1[nb + t] : 0.f;
  }
  int lane = t & 63, w = t >> 6;
  int row16 = lane & 15, kgrp = lane >> 4;

  f32x4 acc[8];
#pragma unroll
  for (int c = 0; c < 8; ++c) acc[c] = (f32x4){0.f, 0.f, 0.f, 0.f};

  int ar = t >> 2, ak0 = (t & 3) * 32;  // A staging: row, 32 k-elems
  int wr = t >> 1, wk0 = (t & 1) * 64;  // W staging: row, 64 k-elems

#pragma unroll 1
  for (int ch = 0; ch < 2; ++ch) {
    __syncthreads();                    //也 protects rs_l/ms_l on ch=0
    // ---- stage A (cast f32 -> bf16, swizzled) ----
    const float* SA = (ch == 0) ? agg2 : h1;
    float scale = (ch == 0) ? 1.f : rs_l[ar];
#pragma unroll
    for (int q = 0; q < 4; ++q) {
      int k8 = ak0 + q * 8;
      float4 f0 = *(const float4*)(SA + (size_t)(nb + ar) * NH + k8);
      float4 f1 = *(const float4*)(SA + (size_t)(nb + ar) * NH + k8 + 4);
      union { unsigned short us[8]; uint4 v; } p;
      p.us[0] = f2bf(f0.x * scale); p.us[1] = f2bf(f0.y * scale);
      p.us[2] = f2bf(f0.z * scale); p.us[3] = f2bf(f0.w * scale);
      p.us[4] = f2bf(f1.x * scale); p.us[5] = f2bf(f1.y * scale);
      p.us[6] = f2bf(f1.z * scale); p.us[7] = f2bf(f1.w * scale);
      *(uint4*)&Asm[ar][k8 ^ ((ar & 7) << 3)] = p.v;
    }
    // ---- stage W ----
    const float* SW = (ch == 0) ? W2rel : W2rt;
#pragma unroll
    for (int q = 0; q < 8; ++q) {
      int k8 = wk0 + q * 8;
      float4 f0 = *(const float4*)(SW + (size_t)wr * NH + k8);
      float4 f1 = *(const float4*)(SW + (size_t)wr * NH + k8 + 4);
      union { unsigned short us[8]; uint4 v; } p;
      p.us[0] = f2bf(f0.x); p.us[1] = f2bf(f0.y);
      p.us[2] = f2bf(f0.z); p.us[3] = f2bf(f0.w);
      p.us[4] = f2bf(f1.x); p.us[5] = f2bf(f1.y);
      p.us[6] = f2bf(f1.z); p.us[7] = f2bf(f1.w);
      *(uint4*)&Wsm[wr][k8 ^ ((wr & 7) << 3)] = p.v;
    }
    __syncthreads();
    // ---- MFMA: 4 K-steps x 8 col-tiles ----
    int sx = (row16 & 7) << 3;
#pragma unroll
    for (int s = 0; s < 4; ++s) {
      int kb = s * 32 + kgrp * 8;
      bf16x8 a = *(const bf16x8*)&Asm[16 * w + row16][kb ^ sx];
#pragma unroll
      for (int c = 0; c < 8; ++c) {
        bf16x8 wv = *(const bf16x8*)&Wsm[c * 16 + row16][kb ^ sx];
        acc[c] = __builtin_amdgcn_mfma_f32_16x16x32_bf16(a, wv, acc[c], 0, 0, 0);
      }
    }
  }

  // ---- epilogue: bias + relu + h2 write (gated) + fused pool2 score ----
  float bb[8], pw[8];
#pragma unroll
  for (int c = 0; c < 8; ++c) {
    bb[c] = b2[c * 16 + row16];
    pw[c] = p2w[c * 16 + row16];
  }
  float q2 = 0.f;
#pragma unroll
  for (int c = 0; c < 8; ++c) q2 += pw[c] * pw[c];
  q2 += __shfl_xor(q2, 1); q2 += __shfl_xor(q2, 2);
  q2 += __shfl_xor(q2, 4); q2 += __shfl_xor(q2, 8);
  float rnorm = rsqrtf(q2);

  float pvp[4] = {0.f, 0.f, 0.f, 0.f};
#pragma unroll
  for (int c = 0; c < 8; ++c) {
#pragma unroll
    for (int r = 0; r < 4; ++r) {
      float u = fmaxf(acc[c][r] + bb[c], 0.f);
      pvp[r] += u * pw[c];
      int rowo = kgrp * 4 + r;
      if (ms_l[16 * w + rowo]) {         // kept2 subset of kept1 -> safe skip
        int n = nb + 16 * w + rowo;
        h2[(size_t)n * NH + c * 16 + row16] = u;
      }
    }
  }
#pragma unroll
  for (int r = 0; r < 4; ++r) {
    float pv = pvp[r];
    pv += __shfl_xor(pv, 1);
    pv += __shfl_xor(pv, 2);
    pv += __shfl_xor(pv, 4);
    pv += __shfl_xor(pv, 8);
    if (row16 == 0) {
      int n = nb + 16 * w + kgrp * 4 + r;
      s2[n] = tanhf(pv * rnorm);
    }
  }
}

// ---------------------------------------------------------------------------
// final combine (32 partial slots per graph)
// ---------------------------------------------------------------------------
__global__ __launch_bounds__(256) void k_final(
    const float* __restrict__ psum1, const float* __restrict__ pmax1,
    const float* __restrict__ psum2, const float* __restrict__ pmax2,
    float* __restrict__ out) {
  int g = blockIdx.x, t = threadIdx.x;
  if (t < 128) {
    float a = 0.f, b = 0.f;
#pragma unroll
    for (int c = 0; c < 32; ++c) {
      a += psum1[(size_t)(g * 32 + c) * NH + t];
      b += psum2[(size_t)(g * 32 + c) * NH + t];
    }
    out[(size_t)g * 256 + t] = a / (float)KP1 + b / (float)KP2;
  } else {
    int f = t - 128;
    float a = -1e30f, b = -1e30f;
#pragma unroll
    for (int c = 0; c < 32; ++c) {
      a = fmaxf(a, pmax1[(size_t)(g * 32 + c) * NH + f]);
      b = fmaxf(b, pmax2[(size_t)(g * 32 + c) * NH + f]);
    }
    out[(size_t)g * 256 + t] = a + b;
  }
}

// ---------------------------------------------------------------------------
extern "C" void kernel_launch(void* const* d_in, const int* in_sizes, int n_in,
                              void* d_out, int out_size, void* d_ws, size_t ws_size,
                              hipStream_t stream) {
  const float* x     = (const float*)d_in[0];
  const int*   eidx  = (const int*)d_in[1];
  const int*   src   = eidx;
  const int*   dst   = eidx + EDGES;
  const float* W1rel = (const float*)d_in[3];
  const float* b1    = (const float*)d_in[4];
  const float* W1rt  = (const float*)d_in[5];
  const float* p1w   = (const float*)d_in[6];
  const float* W2rel = (const float*)d_in[7];
  const float* b2    = (const float*)d_in[8];
  const float* W2rt  = (const float*)d_in[9];
  const float* p2w   = (const float*)d_in[10];
  float* out = (float*)d_out;

  // workspace layout (floats) — h2 aliases agg2 (see k_gemm2)
  float* ws = (float*)d_ws;
  size_t off = 0;
  float* h1    = ws + off; off += (size_t)NODES * NH;
  float* agg2  = ws + off; off += (size_t)NODES * NH;
  float* h2    = agg2;
  float* agg1  = ws + off; off += (size_t)NODES * FIN;
  float* s1    = ws + off; off += NODES;
  float* s2    = ws + off; off += NODES;
  int*   kept1 = (int*)(ws + off); off += NODES;
  int*   kept2 = (int*)(ws + off); off += NODES;
  float* psum1 = ws + off; off += 2048 * NH;
  float* pmax1 = ws + off; off += 2048 * NH;
  float* psum2 = ws + off; off += 2048 * NH;
  float* pmax2 = ws + off; off += 2048 * NH;
  int*   cnt     = (int*)(ws + off); off += NODES;
  int*   rowptr  = (int*)(ws + off); off += NODES + 1;
  int*   cursor  = (int*)(ws + off); off += NODES;
  int*   bsum    = (int*)(ws + off); off += 256;
  int*   col     = (int*)(ws + off); off += EDGES;

  // ---- CSR build ----
  hipMemsetAsync(cnt, 0, (size_t)NODES * sizeof(int), stream);
  k_hist<<<EDGES / 256, 256, 0, stream>>>(dst, cnt);
  k_scan_local<<<NODES / 256, 256, 0, stream>>>(cnt, rowptr, bsum);
  k_scan_final<<<NODES / 256, 256, 0, stream>>>(rowptr, bsum, cursor);
  k_fill<<<EDGES / 256, 256, 0, stream>>>(src, dst, cursor, col);

  // ---- layer 1 ----
  k_gather1<<<NODES / 16, 256, 0, stream>>>(x, rowptr, col, agg1);
  k_gemm1<<<NODES / 64, 256, 0, stream>>>(x, agg1, W1rel, b1, W1rt, p1w,
                                          h1, s1);
  k_topk<<<BATCH, 512, 0, stream>>>(s1, nullptr, kept1, KP1);
  k_readout<<<BATCH * 16, 256, 0, stream>>>(h1, s1, kept1, psum1, pmax1);

  // ---- layer 2 ----
  k_gather2<<<NODES / 4, 256, 0, stream>>>(h1, s1, rowptr, col, kept1, agg2);
  k_gemm2<<<NODES / 64, 256, 0, stream>>>(agg2, h1, s1, kept1, W2rel, W2rt,
                                          b2, p2w, h2, s2);
  k_topk<<<BATCH, 512, 0, stream>>>(s2, kept1, kept2, KP2);
  k_readout<<<BATCH * 16, 256, 0, stream>>>(h2, s2, kept2, psum2, pmax2);
  k_final<<<BATCH, 256, 0, stream>>>(psum1, pmax1, psum2, pmax2, out);
}

// Round 8
// 194.642 us; speedup vs baseline: 1.2039x; 1.0802x over previous
//
#include <hip/hip_runtime.h>
#include <hip/hip_bf16.h>
#include <cmath>

// Problem constants
#define BATCH   64
#define NPG     1024           // nodes per graph
#define NODES   65536          // BATCH*NPG
#define EDGES   524288
#define FIN     14
#define NH      128
#define KP1     820
#define KP2     656

typedef __attribute__((ext_vector_type(8))) short bf16x8;
typedef __attribute__((ext_vector_type(4))) float f32x4;

static __device__ __forceinline__ unsigned short f2bf(float f) {
  __hip_bfloat16 h = __float2bfloat16(f);
  return *reinterpret_cast<unsigned short*>(&h);
}

// ---------------------------------------------------------------------------
// zero cnt (replaces hipMemsetAsync: 256KB fill dispatch cost ~44us in-graph)
// ---------------------------------------------------------------------------
__global__ __launch_bounds__(256) void k_zero(int4* __restrict__ p) {
  p[blockIdx.x * 256 + threadIdx.x] = make_int4(0, 0, 0, 0);
}

// ---------------------------------------------------------------------------
// CSR build (by dst): histogram -> 2-level exclusive scan -> fill
// ---------------------------------------------------------------------------
__global__ __launch_bounds__(256) void k_hist(
    const int* __restrict__ dst, int* __restrict__ cnt) {
  int e = blockIdx.x * 256 + threadIdx.x;
  atomicAdd(&cnt[dst[e]], 1);
}

__global__ __launch_bounds__(256) void k_scan_local(
    const int* __restrict__ cnt, int* __restrict__ rowptr,
    int* __restrict__ bsum) {
  __shared__ int s[256];
  int t = threadIdx.x, b = blockIdx.x;
  int v = cnt[b * 256 + t];
  s[t] = v;
  __syncthreads();
  for (int d = 1; d < 256; d <<= 1) {
    int add = (t >= d) ? s[t - d] : 0;
    __syncthreads();
    s[t] += add;
    __syncthreads();
  }
  rowptr[b * 256 + t] = s[t] - v;      // exclusive, block-local
  if (t == 255) bsum[b] = s[255];
}

// merged base-scan + final: each block redundantly scans bsum[256] in LDS
__global__ __launch_bounds__(256) void k_scan_final(
    int* __restrict__ rowptr, const int* __restrict__ bsum,
    int* __restrict__ cursor) {
  __shared__ int s[256];
  int t = threadIdx.x, b = blockIdx.x;
  int v = bsum[t];
  s[t] = v;
  __syncthreads();
  for (int d = 1; d < 256; d <<= 1) {
    int add = (t >= d) ? s[t - d] : 0;
    __syncthreads();
    s[t] += add;
    __syncthreads();
  }
  int base = (b == 0) ? 0 : s[b - 1];    // exclusive prefix of block b
  int id = b * 256 + t;
  int v2 = rowptr[id] + base;
  rowptr[id] = v2;
  cursor[id] = v2;
  if (id == 0) rowptr[NODES] = EDGES;
}

__global__ __launch_bounds__(256) void k_fill(
    const int* __restrict__ src, const int* __restrict__ dst,
    int* __restrict__ cursor, int* __restrict__ col) {
  int e = blockIdx.x * 256 + threadIdx.x;
  int pos = atomicAdd(&cursor[dst[e]], 1);
  col[pos] = src[e];
}

// ---------------------------------------------------------------------------
// pre-convert W2 = [W2rel | W2root] to bf16 MFMA B-fragment layout:
// Wfrag[(c*8+sg)*64 + lane] = 8 bf16 at out-row c*16+(lane&15),
//                             k = (sg&3)*32 + (lane>>4)*8 (sg<4: W2rel else W2rt)
// 64 KB total, L2-hot, read coalesced (16B/lane) by every gemm2 wave.
// ---------------------------------------------------------------------------
__global__ __launch_bounds__(256) void k_prep_w(
    const float* __restrict__ W2rel, const float* __restrict__ W2rt,
    unsigned short* __restrict__ Wfrag) {
  int id = blockIdx.x * 256 + threadIdx.x;    // 4096 total
  int lane = id & 63, sg = (id >> 6) & 7, c = id >> 9;
  const float* SW = (sg < 4) ? W2rel : W2rt;
  int o = c * 16 + (lane & 15);
  int k = (sg & 3) * 32 + (lane >> 4) * 8;
  float4 f0 = *(const float4*)(SW + (size_t)o * NH + k);
  float4 f1 = *(const float4*)(SW + (size_t)o * NH + k + 4);
  union { unsigned short us[8]; uint4 v; } p;
  p.us[0] = f2bf(f0.x); p.us[1] = f2bf(f0.y);
  p.us[2] = f2bf(f0.z); p.us[3] = f2bf(f0.w);
  p.us[4] = f2bf(f1.x); p.us[5] = f2bf(f1.y);
  p.us[6] = f2bf(f1.z); p.us[7] = f2bf(f1.w);
  *(uint4*)(Wfrag + (size_t)id * 8) = p.v;
}

// ---------------------------------------------------------------------------
// conv1 aggregation via CSR gather (XCD-swizzled for per-graph L2 locality)
// ---------------------------------------------------------------------------
__global__ __launch_bounds__(256) void k_gather1(
    const float* __restrict__ x, const int* __restrict__ rowptr,
    const int* __restrict__ col, float* __restrict__ agg1) {
  int bid = blockIdx.x;                       // 4096 blocks, 512 per XCD chunk
  int swz = (bid & 7) * 512 + (bid >> 3);
  int t = threadIdx.x;
  int gi = t >> 4, l = t & 15;
  int n = swz * 16 + gi;
  int rs = rowptr[n], re = rowptr[n + 1];
  if (l < FIN) {
    float acc = 0.f;
    for (int j = rs; j < re; ++j) {
      int v = col[j];
      acc += x[(size_t)v * FIN + l];
    }
    agg1[(size_t)n * FIN + l] = acc;
  }
}

// ---------------------------------------------------------------------------
// conv1 GEMM + relu + fused pool1 score (norm computed inline via shfl).
// Block 256 thr / 64 nodes; thread = 4 nodes x 8 outs (cols og*4+j, 64+og*4+j)
// ---------------------------------------------------------------------------
__global__ __launch_bounds__(256) void k_gemm1(
    const float* __restrict__ x, const float* __restrict__ agg1,
    const float* __restrict__ Wrel, const float* __restrict__ brel,
    const float* __restrict__ Wroot, const float* __restrict__ p1w,
    float* __restrict__ h1, float* __restrict__ s1) {
  __shared__ float As[64 * FIN];
  __shared__ float Xs[64 * FIN];
  __shared__ float Wl[2 * FIN][NH];
  int t = threadIdx.x;
  int nb = blockIdx.x * 64;
  for (int i = t; i < 64 * FIN; i += 256) {
    As[i] = agg1[(size_t)nb * FIN + i];
    Xs[i] = x[(size_t)nb * FIN + i];
  }
  for (int i = t; i < NH * FIN; i += 256) {
    int o = i / FIN, k = i - o * FIN;
    Wl[k][o]       = Wrel[i];
    Wl[k + FIN][o] = Wroot[i];
  }
  __syncthreads();
  int og = t & 15, ng = t >> 4, ra = ng * 4;
  float bb[8], pw[8];
#pragma unroll
  for (int j = 0; j < 4; ++j) {
    int c0 = og * 4 + j, c1 = 64 + og * 4 + j;
    bb[j] = brel[c0]; bb[j + 4] = brel[c1];
    pw[j] = p1w[c0];  pw[j + 4] = p1w[c1];
  }
  // rn1 = 1/||p1w||: 16-lane og-group covers all 128 cols
  float q = 0.f;
#pragma unroll
  for (int j = 0; j < 8; ++j) q += pw[j] * pw[j];
  q += __shfl_xor(q, 1); q += __shfl_xor(q, 2);
  q += __shfl_xor(q, 4); q += __shfl_xor(q, 8);
  float rnorm = rsqrtf(q);

  float acc[4][8];
#pragma unroll
  for (int i = 0; i < 4; ++i)
#pragma unroll
    for (int j = 0; j < 8; ++j) acc[i][j] = bb[j];
#pragma unroll
  for (int k = 0; k < FIN; ++k) {
    float4 w0 = *(const float4*)&Wl[k][og * 4];
    float4 w1 = *(const float4*)&Wl[k][64 + og * 4];
#pragma unroll
    for (int i = 0; i < 4; ++i) {
      float a = As[(ra + i) * FIN + k];
      acc[i][0] += a * w0.x; acc[i][1] += a * w0.y;
      acc[i][2] += a * w0.z; acc[i][3] += a * w0.w;
      acc[i][4] += a * w1.x; acc[i][5] += a * w1.y;
      acc[i][6] += a * w1.z; acc[i][7] += a * w1.w;
    }
  }
#pragma unroll
  for (int k = 0; k < FIN; ++k) {
    float4 w0 = *(const float4*)&Wl[FIN + k][og * 4];
    float4 w1 = *(const float4*)&Wl[FIN + k][64 + og * 4];
#pragma unroll
    for (int i = 0; i < 4; ++i) {
      float a = Xs[(ra + i) * FIN + k];
      acc[i][0] += a * w0.x; acc[i][1] += a * w0.y;
      acc[i][2] += a * w0.z; acc[i][3] += a * w0.w;
      acc[i][4] += a * w1.x; acc[i][5] += a * w1.y;
      acc[i][6] += a * w1.z; acc[i][7] += a * w1.w;
    }
  }
#pragma unroll
  for (int i = 0; i < 4; ++i) {
    int n = nb + ra + i;
    float pv = 0.f;
#pragma unroll
    for (int j = 0; j < 8; ++j) {
      float v = fmaxf(acc[i][j], 0.f);
      acc[i][j] = v;
      pv += v * pw[j];
    }
    *(float4*)(h1 + (size_t)n * NH + og * 4) =
        make_float4(acc[i][0], acc[i][1], acc[i][2], acc[i][3]);
    *(float4*)(h1 + (size_t)n * NH + 64 + og * 4) =
        make_float4(acc[i][4], acc[i][5], acc[i][6], acc[i][7]);
    pv += __shfl_xor(pv, 1);
    pv += __shfl_xor(pv, 2);
    pv += __shfl_xor(pv, 4);
    pv += __shfl_xor(pv, 8);
    if (og == 0) s1[n] = tanhf(pv * rnorm);
  }
}

// ---------------------------------------------------------------------------
// exact per-graph top-K: 512 threads, all-active bitonic over 1024 keys
// ---------------------------------------------------------------------------
__global__ __launch_bounds__(512) void k_topk(
    const float* __restrict__ score, const int* __restrict__ mask_in,
    int* __restrict__ kept, int K) {
  __shared__ unsigned long long keys[1024];
  int t = threadIdx.x, g = blockIdx.x;
  for (int i = t; i < 1024; i += 512) {
    int n = g * NPG + i;
    unsigned int inv;
    if (mask_in && !mask_in[n]) {
      inv = 0xFFFFFFFFu;
    } else {
      unsigned int u   = __float_as_uint(score[n]);
      unsigned int ord = (u & 0x80000000u) ? ~u : (u | 0x80000000u);
      inv = ~ord;
    }
    keys[i] = ((unsigned long long)inv << 32) | (unsigned int)i;
  }
  __syncthreads();
  for (int k = 2; k <= 1024; k <<= 1) {
    for (int j = k >> 1; j > 0; j >>= 1) {
      int i = ((t & ~(j - 1)) << 1) | (t & (j - 1));
      int p = i | j;
      unsigned long long a = keys[i], b = keys[p];
      bool up = ((i & k) == 0);
      if ((a > b) == up) { keys[i] = b; keys[p] = a; }
      __syncthreads();
    }
  }
  for (int i = t; i < 1024; i += 512) {
    int idx = (int)(keys[i] & 0xFFFFFFFFu);
    kept[g * NPG + idx] = (i < K) ? 1 : 0;
  }
}

// ---------------------------------------------------------------------------
// readout partials over kept nodes: v = h[n]*s[n]  (read-only)
// ---------------------------------------------------------------------------
__global__ __launch_bounds__(256) void k_readout(
    const float* __restrict__ h, const float* __restrict__ s,
    const int* __restrict__ kept, float* __restrict__ psum,
    float* __restrict__ pmax) {
  int g = blockIdx.x >> 4, c = blockIdx.x & 15;
  int f = threadIdx.x & 127, half = threadIdx.x >> 7;
  int nbase = g * NPG + c * 64 + half;
  float sum = 0.f, mx = -1e30f;
  for (int i = 0; i < 64; i += 2) {
    int n = nbase + i;
    if (kept[n]) {
      float v = h[(size_t)n * NH + f] * s[n];
      sum += v;
      mx = fmaxf(mx, v);
    }
  }
  int slot = blockIdx.x * 2 + half;
  psum[(size_t)slot * NH + f] = sum;
  pmax[(size_t)slot * NH + f] = mx;
}

// ---------------------------------------------------------------------------
// conv2 aggregation: one wave per kept dst row; scale s1*kept applied on the
// fly. XCD-swizzled: graph-local L2 reuse of h1 rows.
// ---------------------------------------------------------------------------
__global__ __launch_bounds__(256) void k_gather2(
    const float* __restrict__ h1, const float* __restrict__ s1,
    const int* __restrict__ rowptr, const int* __restrict__ col,
    const int* __restrict__ kept1, float* __restrict__ agg2) {
  int bid = blockIdx.x;                       // 16384 blocks, 2048 per XCD
  int swz = (bid & 7) * 2048 + (bid >> 3);
  int wave = threadIdx.x >> 6, lane = threadIdx.x & 63;
  int d = swz * 4 + wave;
  if (!kept1[d]) return;                      // row never consumed downstream
  int rs = rowptr[d], re = rowptr[d + 1];
  int deg = re - rs;
  int colv = 0; float sv = 0.f;
  if (lane < deg) {
    colv = col[rs + lane];
    sv = kept1[colv] ? s1[colv] : 0.f;
  }
  int m = deg < 64 ? deg : 64;
  float ax = 0.f, ay = 0.f;
  int nfull = m & ~3;
  int j = 0;
  for (; j < nfull; j += 4) {
    int v0 = __shfl(colv, j);
    int v1 = __shfl(colv, j + 1);
    int v2 = __shfl(colv, j + 2);
    int v3 = __shfl(colv, j + 3);
    float f0 = __shfl(sv, j);
    float f1 = __shfl(sv, j + 1);
    float f2 = __shfl(sv, j + 2);
    float f3 = __shfl(sv, j + 3);
    float2 a = *(const float2*)(h1 + (size_t)v0 * NH + lane * 2);
    float2 b = *(const float2*)(h1 + (size_t)v1 * NH + lane * 2);
    float2 c = *(const float2*)(h1 + (size_t)v2 * NH + lane * 2);
    float2 e = *(const float2*)(h1 + (size_t)v3 * NH + lane * 2);
    ax += a.x * f0 + b.x * f1 + c.x * f2 + e.x * f3;
    ay += a.y * f0 + b.y * f1 + c.y * f2 + e.y * f3;
  }
  for (; j < m; ++j) {
    int v = __shfl(colv, j);
    float f = __shfl(sv, j);
    float2 a = *(const float2*)(h1 + (size_t)v * NH + lane * 2);
    ax += a.x * f; ay += a.y * f;
  }
  for (int jj = rs + 64; jj < re; ++jj) {      // deg>64 fallback (≈never)
    int v = col[jj];
    float f = kept1[v] ? s1[v] : 0.f;
    float2 a = *(const float2*)(h1 + (size_t)v * NH + lane * 2);
    ax += a.x * f; ay += a.y * f;
  }
  *(float2*)(agg2 + (size_t)d * NH + lane * 2) = make_float2(ax, ay);
}

// ---------------------------------------------------------------------------
// conv2 via bf16 MFMA — BARRIER-FREE, LDS-FREE.
// Per wave: 16 rows. A fragments (row=lane&15 of tile, k=(lane>>4)*8) are
// converted f32->bf16 straight into registers from agg2 (K 0..127) and
// h1*s1*kept (K 128..255). W fragments stream from the 64KB L2-hot Wfrag
// table (k_prep_w) with fully-coalesced 16B/lane loads. f32 accumulate.
// D layout: col=lane&15, row=(lane>>4)*4+reg (m89). h2 ALIASES agg2 (own
// rows only, write gated to kept rows; dropped rows' s2 garbage is masked by
// topk2's mask_in). XCD-swizzle matches gather2's writer map.
// ---------------------------------------------------------------------------
__global__ __launch_bounds__(256) void k_gemm2(
    const float* __restrict__ agg2, const float* __restrict__ h1,
    const float* __restrict__ s1, const int* __restrict__ kept1,
    const unsigned short* __restrict__ Wfrag, const float* __restrict__ b2,
    const float* __restrict__ p2w, float* __restrict__ h2,
    float* __restrict__ s2) {
  int t = threadIdx.x;
  int bid = blockIdx.x;                 // 1024 blocks, 128 per XCD chunk
  int swz = (bid & 7) * 128 + (bid >> 3);
  int nb = swz * 64;
  int lane = t & 63, w = t >> 6;
  int row16 = lane & 15, kgrp = lane >> 4;
  int myrow = nb + 16 * w + row16;

  // ---- A fragments into registers ----
  const float* SA0 = agg2 + (size_t)myrow * NH;
  const float* SA1 = h1 + (size_t)myrow * NH;
  float sc1 = kept1[myrow] ? s1[myrow] : 0.f;
  bf16x8 a[8];
#pragma unroll
  for (int s = 0; s < 8; ++s) {
    const float* S = (s < 4) ? SA0 : SA1;
    float sc = (s < 4) ? 1.f : sc1;
    int k = (s & 3) * 32 + kgrp * 8;
    float4 f0 = *(const float4*)(S + k);
    float4 f1 = *(const float4*)(S + k + 4);
    union { unsigned short us[8]; bf16x8 v; } p;
    p.us[0] = f2bf(f0.x * sc); p.us[1] = f2bf(f0.y * sc);
    p.us[2] = f2bf(f0.z * sc); p.us[3] = f2bf(f0.w * sc);
    p.us[4] = f2bf(f1.x * sc); p.us[5] = f2bf(f1.y * sc);
    p.us[6] = f2bf(f1.z * sc); p.us[7] = f2bf(f1.w * sc);
    a[s] = p.v;
  }

  // ---- MFMA: stream W fragments from L2 ----
  f32x4 acc[8];
#pragma unroll
  for (int c = 0; c < 8; ++c) acc[c] = (f32x4){0.f, 0.f, 0.f, 0.f};
  const bf16x8* WF = (const bf16x8*)Wfrag;
#pragma unroll
  for (int c = 0; c < 8; ++c) {
#pragma unroll
    for (int s = 0; s < 8; ++s) {
      bf16x8 wv = WF[(c * 8 + s) * 64 + lane];
      acc[c] = __builtin_amdgcn_mfma_f32_16x16x32_bf16(a[s], wv, acc[c], 0, 0, 0);
    }
  }

  // ---- epilogue: bias + relu + gated h2 write + fused pool2 score ----
  float bb[8], pw[8];
#pragma unroll
  for (int c = 0; c < 8; ++c) {
    bb[c] = b2[c * 16 + row16];
    pw[c] = p2w[c * 16 + row16];
  }
  float q2 = 0.f;
#pragma unroll
  for (int c = 0; c < 8; ++c) q2 += pw[c] * pw[c];
  q2 += __shfl_xor(q2, 1); q2 += __shfl_xor(q2, 2);
  q2 += __shfl_xor(q2, 4); q2 += __shfl_xor(q2, 8);
  float rnorm = rsqrtf(q2);

  int msr[4];
#pragma unroll
  for (int r = 0; r < 4; ++r) msr[r] = kept1[nb + 16 * w + kgrp * 4 + r];

  float pvp[4] = {0.f, 0.f, 0.f, 0.f};
#pragma unroll
  for (int c = 0; c < 8; ++c) {
#pragma unroll
    for (int r = 0; r < 4; ++r) {
      float u = fmaxf(acc[c][r] + bb[c], 0.f);
      pvp[r] += u * pw[c];
      if (msr[r]) {                      // kept2 subset of kept1 -> safe skip
        int n = nb + 16 * w + kgrp * 4 + r;
        h2[(size_t)n * NH + c * 16 + row16] = u;
      }
    }
  }
#pragma unroll
  for (int r = 0; r < 4; ++r) {
    float pv = pvp[r];
    pv += __shfl_xor(pv, 1);
    pv += __shfl_xor(pv, 2);
    pv += __shfl_xor(pv, 4);
    pv += __shfl_xor(pv, 8);
    if (row16 == 0) {
      int n = nb + 16 * w + kgrp * 4 + r;
      s2[n] = tanhf(pv * rnorm);
    }
  }
}

// ---------------------------------------------------------------------------
// final combine (32 partial slots per graph)
// ---------------------------------------------------------------------------
__global__ __launch_bounds__(256) void k_final(
    const float* __restrict__ psum1, const float* __restrict__ pmax1,
    const float* __restrict__ psum2, const float* __restrict__ pmax2,
    float* __restrict__ out) {
  int g = blockIdx.x, t = threadIdx.x;
  if (t < 128) {
    float a = 0.f, b = 0.f;
#pragma unroll
    for (int c = 0; c < 32; ++c) {
      a += psum1[(size_t)(g * 32 + c) * NH + t];
      b += psum2[(size_t)(g * 32 + c) * NH + t];
    }
    out[(size_t)g * 256 + t] = a / (float)KP1 + b / (float)KP2;
  } else {
    int f = t - 128;
    float a = -1e30f, b = -1e30f;
#pragma unroll
    for (int c = 0; c < 32; ++c) {
      a = fmaxf(a, pmax1[(size_t)(g * 32 + c) * NH + f]);
      b = fmaxf(b, pmax2[(size_t)(g * 32 + c) * NH + f]);
    }
    out[(size_t)g * 256 + t] = a + b;
  }
}

// ---------------------------------------------------------------------------
extern "C" void kernel_launch(void* const* d_in, const int* in_sizes, int n_in,
                              void* d_out, int out_size, void* d_ws, size_t ws_size,
                              hipStream_t stream) {
  const float* x     = (const float*)d_in[0];
  const int*   eidx  = (const int*)d_in[1];
  const int*   src   = eidx;
  const int*   dst   = eidx + EDGES;
  const float* W1rel = (const float*)d_in[3];
  const float* b1    = (const float*)d_in[4];
  const float* W1rt  = (const float*)d_in[5];
  const float* p1w   = (const float*)d_in[6];
  const float* W2rel = (const float*)d_in[7];
  const float* b2    = (const float*)d_in[8];
  const float* W2rt  = (const float*)d_in[9];
  const float* p2w   = (const float*)d_in[10];
  float* out = (float*)d_out;

  // workspace layout (floats) — h2 aliases agg2 (see k_gemm2)
  float* ws = (float*)d_ws;
  size_t off = 0;
  float* h1    = ws + off; off += (size_t)NODES * NH;
  float* agg2  = ws + off; off += (size_t)NODES * NH;
  float* h2    = agg2;
  float* agg1  = ws + off; off += (size_t)NODES * FIN;
  float* s1    = ws + off; off += NODES;
  float* s2    = ws + off; off += NODES;
  int*   kept1 = (int*)(ws + off); off += NODES;
  int*   kept2 = (int*)(ws + off); off += NODES;
  float* psum1 = ws + off; off += 2048 * NH;
  float* pmax1 = ws + off; off += 2048 * NH;
  float* psum2 = ws + off; off += 2048 * NH;
  float* pmax2 = ws + off; off += 2048 * NH;
  unsigned short* Wfrag = (unsigned short*)(ws + off); off += 16384; // 64 KB
  int*   cnt     = (int*)(ws + off); off += NODES;
  int*   rowptr  = (int*)(ws + off); off += NODES + 1;
  int*   cursor  = (int*)(ws + off); off += NODES;
  int*   bsum    = (int*)(ws + off); off += 256;
  int*   col     = (int*)(ws + off); off += EDGES;

  // ---- CSR build ----
  k_zero<<<64, 256, 0, stream>>>((int4*)cnt);
  k_hist<<<EDGES / 256, 256, 0, stream>>>(dst, cnt);
  k_scan_local<<<NODES / 256, 256, 0, stream>>>(cnt, rowptr, bsum);
  k_scan_final<<<NODES / 256, 256, 0, stream>>>(rowptr, bsum, cursor);
  k_fill<<<EDGES / 256, 256, 0, stream>>>(src, dst, cursor, col);

  // ---- weight prep (independent) ----
  k_prep_w<<<16, 256, 0, stream>>>(W2rel, W2rt, Wfrag);

  // ---- layer 1 ----
  k_gather1<<<NODES / 16, 256, 0, stream>>>(x, rowptr, col, agg1);
  k_gemm1<<<NODES / 64, 256, 0, stream>>>(x, agg1, W1rel, b1, W1rt, p1w,
                                          h1, s1);
  k_topk<<<BATCH, 512, 0, stream>>>(s1, nullptr, kept1, KP1);
  k_readout<<<BATCH * 16, 256, 0, stream>>>(h1, s1, kept1, psum1, pmax1);

  // ---- layer 2 ----
  k_gather2<<<NODES / 4, 256, 0, stream>>>(h1, s1, rowptr, col, kept1, agg2);
  k_gemm2<<<NODES / 64, 256, 0, stream>>>(agg2, h1, s1, kept1, Wfrag,
                                          b2, p2w, h2, s2);
  k_topk<<<BATCH, 512, 0, stream>>>(s2, kept1, kept2, KP2);
  k_readout<<<BATCH * 16, 256, 0, stream>>>(h2, s2, kept2, psum2, pmax2);
  k_final<<<BATCH, 256, 0, stream>>>(psum1, pmax1, psum2, pmax2, out);
}